// Round 6
// baseline (374.432 us; speedup 1.0000x reference)
//
#include <hip/hip_runtime.h>
#include <math.h>

// RVQECell on MI355X.
// State: [B=32][2^19] fp32. Lane l <-> state bit (18-l). inout = bits 13..18,
// work = bits 1..12, ancilla = bit 0 (spectator).
//
// R11 (vs R10 @ 328 us, main=154):
//  Residual (total - main) = 174 us vs floors of ~10 (tables) + ~30 (out).
//  Prime suspect: out_kernel's 192 table loads/thread at 32 KB stride
//  (256 useful B/wave-inst, 6 MiB slice > 4 MiB L2/XCD, ~2 waves/SIMD ->
//  latency uncovered). R11:
//   (a) out tables written TRANSPOSED + PRE-SWIZZLED in global:
//       x=(m<<12)|w12 stored at w12*32+((m+w12)&31) -> per-block slice is
//       a contiguous 32 KB chunk per stage.
//   (b) out_kernel: after a[64] extraction the 64 KiB tile in LDS is dead ->
//       reuse it: 3 phases x {copy 2 tables coalesced (float4), butterfly
//       2 stages reading LDS (<=2-way conflicts, free)}.
//   (c) tables_kernel: 8 entries/thread (grid 64x54), 3456 blocks vs 27648.
//   (d) main_kernel untouched (control; 154 us proven).
//  Discriminator: total ~215 -> strided loads were it; >=300 -> overhead ->
//  fuse kernels next round.

#define BIAS_F 1.57079632679489662f

typedef float v4f __attribute__((ext_vector_type(4)));

__device__ __forceinline__ float4 ntload4(const float* p) {
    v4f v = __builtin_nontemporal_load((const v4f*)p);
    return make_float4(v.x, v.y, v.z, v.w);
}
__device__ __forceinline__ void ntstore4(float* p, float4 f) {
    v4f v = {f.x, f.y, f.z, f.w};
    __builtin_nontemporal_store(v, (v4f*)p);
}

// ---- LDS bank swizzle: fold bits 7..5 into 4..2 (keeps float4 contiguity) ----
__device__ __forceinline__ int SW(int i) { return i ^ ((i >> 3) & 0x1C); }
__device__ __forceinline__ float4 ldsld4(const float* st, int i) {
    return *(const float4*)&st[SW(i)];
}
__device__ __forceinline__ void ldsst4(float* st, int i, float4 v) {
    *(float4*)&st[SW(i)] = v;
}

#define LD2(p) (*(const float2*)(p))
#define LD4(p) (*(const float4*)(p))

// rotation on pairs (A.k, B.k); e = (c01,s01,c23,s23); .x/.y share angle (bit0)
__device__ __forceinline__ void rot4(float4& A, float4& B, float4 e) {
    float ax = A.x, ay = A.y, az = A.z, aw = A.w;
    A.x = e.x * ax - e.y * B.x;  B.x = e.y * ax + e.x * B.x;
    A.y = e.x * ay - e.y * B.y;  B.y = e.y * ay + e.x * B.y;
    A.z = e.z * az - e.w * B.z;  B.z = e.w * az + e.z * B.z;
    A.w = e.z * aw - e.w * B.w;  B.w = e.w * aw + e.z * B.w;
}
// rotation within a quad: pairs (x,z),(y,w)  (target = amp bit 1)
__device__ __forceinline__ void rotq(float4& P, float c, float s) {
    float px = P.x, py = P.y;
    P.x = c * px - s * P.z;  P.z = s * px + c * P.z;
    P.y = c * py - s * P.w;  P.w = s * py + c * P.w;
}

// Table layout (float2 units, tab2 = (float2*)tab):
//  n = 0..47 (main):   tab2[n*131072 + (hi<<8|tid)] = {cos, sin}
//  n = 48..53 (out):   transposed+pre-swizzled:
//                      tab2[n*131072 + w12*32 + ((m + w12)&31)]
//                      where m = x>>12 (5 inout-control bits), w12 = x&4095.

// ============================ K1: tables ============================
// 8 entries per thread: block (bx, n) covers hi = bx*8 .. bx*8+7, tid 0..255.
__global__ __launch_bounds__(256) void tables_kernel(
    const float* __restrict__ w_in1, const float* __restrict__ w_in2,
    const float* __restrict__ w_k1,  const float* __restrict__ w_k2,
    const float* __restrict__ w_out1, const float* __restrict__ w_out2,
    float* __restrict__ tab)
{
    const int n = blockIdx.y;
    const int bx = blockIdx.x;       // hi group (8 values)
    const int tid = threadIdx.x;     // x bits 7..0
    const float* th1;
    const float* th2;
    if (n < 12)      { th1 = w_in1 + n * 17;         th2 = w_in2 + n * 289; }
    else if (n < 48) { th1 = w_k1 + (n - 12) * 17;   th2 = w_k2 + (n - 12) * 289; }
    else             { th1 = w_out1 + (n - 48) * 17; th2 = w_out2 + (n - 48) * 289; }

    float bt[8];
#pragma unroll
    for (int j = 0; j < 8; ++j) bt[j] = (float)((tid >> (7 - j)) & 1);

#pragma unroll 1
    for (int k = 0; k < 8; ++k) {
        const int hi = bx * 8 + k;   // wave-uniform

        // ---- uniform hi part: phi_hi + cross coefficients C[a] ----
        float phi_hi = BIAS_F;
        float C[8];
#pragma unroll
        for (int a = 0; a < 8; ++a) C[a] = th1[9 + a];
#pragma unroll
        for (int i = 0; i < 9; ++i) {
            if ((hi >> (8 - i)) & 1) {
                float acc = th1[i];
#pragma unroll
                for (int j = i + 1; j < 9; ++j)
                    if ((hi >> (8 - j)) & 1) acc += th2[i * 17 + j];
                phi_hi += acc;
#pragma unroll
                for (int a = 0; a < 8; ++a) C[a] += th2[i * 17 + 9 + a];
            }
        }

        // ---- per-thread lo part: 36 FMA ----
        float phi = phi_hi;
#pragma unroll
        for (int a = 0; a < 8; ++a) {
            float acc = C[a];
#pragma unroll
            for (int b2 = a + 1; b2 < 8; ++b2) acc += bt[b2] * th2[(9 + a) * 17 + 9 + b2];
            phi += bt[a] * acc;
        }

        float sp, cp;
        sincosf(phi, &sp, &cp);
        float c2 = cp * cp, s2 = sp * sp;
        float d = c2 * c2 + s2 * s2;           // >= 0.25 always
        float r = rsqrtf(d);
        r = r * (1.5f - 0.5f * d * r * r);     // one Newton step

        size_t idx;
        if (n < 48) {
            idx = (size_t)n * 131072 + (size_t)((hi << 8) | tid);
        } else {
            const int m = hi >> 4;                       // x bits 16..12
            const int w12 = ((hi & 15) << 8) | tid;      // x bits 11..0
            idx = (size_t)n * 131072 + (size_t)(w12 * 32 + ((m + w12) & 31));
        }
        ((float2*)tab)[idx] = make_float2(c2 * r, s2 * r);
    }
}

// ============================ K2: main fused ============================
// High pass, targets {PA,PA-1,PA-2}; unpacked (c,s) table regs (12 float4)
// loaded once, reused for both batch slots. t* point at float2 data
// (float-indexed: angle x lives at [2x]).
template <int PA, bool NEUR>
__device__ __forceinline__ void pass_hi2(float* l0, float* l1, int t8,
    const float* tA, const float* tB, const float* tC,
    float cA, float sA, float cB, float sB, float cC, float sC)
{
    const int lowb = PA - 4;
    const int low = t8 & ((1 << lowb) - 1);
    const int high = t8 >> lowb;
    const int i0 = (high << (PA + 1)) | (low << 2);
    const int x0 = (high << (PA - 1)) | (low << 1);
    const int oa = 1 << PA, ob = oa >> 1, oc = oa >> 2;
    const int dhi = oa >> 2, dlo = oa >> 3;
    float4 ea00, ea01, ea10, ea11, eb00, eb01, eb10, eb11, ec00, ec01, ec10, ec11;
    if (NEUR) {
        ea00 = LD4(&tA[2 * x0]);            ea01 = LD4(&tA[2 * (x0 + dlo)]);
        ea10 = LD4(&tA[2 * (x0 + dhi)]);    ea11 = LD4(&tA[2 * (x0 + dhi + dlo)]);
        eb00 = LD4(&tB[2 * x0]);            eb01 = LD4(&tB[2 * (x0 + dlo)]);
        eb10 = LD4(&tB[2 * (x0 + dhi)]);    eb11 = LD4(&tB[2 * (x0 + dhi + dlo)]);
        ec00 = LD4(&tC[2 * x0]);            ec01 = LD4(&tC[2 * (x0 + dlo)]);
        ec10 = LD4(&tC[2 * (x0 + dhi)]);    ec11 = LD4(&tC[2 * (x0 + dhi + dlo)]);
    } else {
        ea00 = ea01 = ea10 = ea11 = make_float4(cA, sA, cA, sA);
        eb00 = eb01 = eb10 = eb11 = make_float4(cB, sB, cB, sB);
        ec00 = ec01 = ec10 = ec11 = make_float4(cC, sC, cC, sC);
    }
#pragma unroll
    for (int s = 0; s < 2; ++s) {
        float* sl = (s == 0) ? l0 : l1;
        float4 Q000 = ldsld4(sl, i0),            Q001 = ldsld4(sl, i0 + oc);
        float4 Q010 = ldsld4(sl, i0 + ob),       Q011 = ldsld4(sl, i0 + ob + oc);
        float4 Q100 = ldsld4(sl, i0 + oa),       Q101 = ldsld4(sl, i0 + oa + oc);
        float4 Q110 = ldsld4(sl, i0 + oa + ob),  Q111 = ldsld4(sl, i0 + oa + ob + oc);
        // target PA
        rot4(Q000, Q100, ea00); rot4(Q001, Q101, ea01);
        rot4(Q010, Q110, ea10); rot4(Q011, Q111, ea11);
        // target PA-1
        rot4(Q000, Q010, eb00); rot4(Q001, Q011, eb01);
        rot4(Q100, Q110, eb10); rot4(Q101, Q111, eb11);
        // target PA-2
        rot4(Q000, Q001, ec00); rot4(Q010, Q011, ec01);
        rot4(Q100, Q101, ec10); rot4(Q110, Q111, ec11);
        ldsst4(sl, i0, Q000);            ldsst4(sl, i0 + oc, Q001);
        ldsst4(sl, i0 + ob, Q010);       ldsst4(sl, i0 + ob + oc, Q011);
        ldsst4(sl, i0 + oa, Q100);       ldsst4(sl, i0 + oa + oc, Q101);
        ldsst4(sl, i0 + oa + ob, Q110);  ldsst4(sl, i0 + oa + ob + oc, Q111);
    }
}

// Low pass, targets {3,2,1}. Thread owns amps i0..i0+31 (8 angles x0..x0+7).
template <bool NEUR>
__device__ __forceinline__ void pass_lo2(float* l0, float* l1, int t8,
    const float* tA, const float* tB, const float* tC,
    float cA, float sA, float cB, float sB, float cC, float sC)
{
    const int i0 = t8 << 5, x0 = t8 << 3;
    float4 ea0, ea1, ea2, ea3, eb0, eb1, eb2, eb3, ec0, ec1, ec2, ec3;
    if (NEUR) {
        ea0 = LD4(&tA[2 * x0]);      ea1 = LD4(&tA[2 * x0 + 4]);
        ea2 = LD4(&tA[2 * x0 + 8]);  ea3 = LD4(&tA[2 * x0 + 12]);
        eb0 = LD4(&tB[2 * x0]);      eb1 = LD4(&tB[2 * x0 + 4]);
        eb2 = LD4(&tB[2 * x0 + 8]);  eb3 = LD4(&tB[2 * x0 + 12]);
        ec0 = LD4(&tC[2 * x0]);      ec1 = LD4(&tC[2 * x0 + 4]);
        ec2 = LD4(&tC[2 * x0 + 8]);  ec3 = LD4(&tC[2 * x0 + 12]);
    } else {
        ea0 = ea1 = ea2 = ea3 = make_float4(cA, sA, cA, sA);
        eb0 = eb1 = eb2 = eb3 = make_float4(cB, sB, cB, sB);
        ec0 = ec1 = ec2 = ec3 = make_float4(cC, sC, cC, sC);
    }
#pragma unroll
    for (int s = 0; s < 2; ++s) {
        float* sl = (s == 0) ? l0 : l1;
        float4 Q0 = ldsld4(sl, i0),      Q1 = ldsld4(sl, i0 + 4);
        float4 Q2 = ldsld4(sl, i0 + 8),  Q3 = ldsld4(sl, i0 + 12);
        float4 Q4 = ldsld4(sl, i0 + 16), Q5 = ldsld4(sl, i0 + 20);
        float4 Q6 = ldsld4(sl, i0 + 24), Q7 = ldsld4(sl, i0 + 28);
        // target 3: pairs (k, k+2)
        rot4(Q0, Q2, ea0); rot4(Q1, Q3, ea1); rot4(Q4, Q6, ea2); rot4(Q5, Q7, ea3);
        // target 2: pairs (k, k+1)
        rot4(Q0, Q1, eb0); rot4(Q2, Q3, eb1); rot4(Q4, Q5, eb2); rot4(Q6, Q7, eb3);
        // target 1: in-quad
        rotq(Q0, ec0.x, ec0.y); rotq(Q1, ec0.z, ec0.w);
        rotq(Q2, ec1.x, ec1.y); rotq(Q3, ec1.z, ec1.w);
        rotq(Q4, ec2.x, ec2.y); rotq(Q5, ec2.z, ec2.w);
        rotq(Q6, ec3.x, ec3.y); rotq(Q7, ec3.z, ec3.w);
        ldsst4(sl, i0, Q0);      ldsst4(sl, i0 + 4, Q1);
        ldsst4(sl, i0 + 8, Q2);  ldsst4(sl, i0 + 12, Q3);
        ldsst4(sl, i0 + 16, Q4); ldsst4(sl, i0 + 20, Q5);
        ldsst4(sl, i0 + 24, Q6); ldsst4(sl, i0 + 28, Q7);
    }
}

__global__ __launch_bounds__(256, 2) void main_kernel(
    const float* __restrict__ batch, const float* __restrict__ w_u,
    const int* __restrict__ inputs, const float* __restrict__ tab,
    float* __restrict__ psi, float* __restrict__ probs)
{
    __shared__ __align__(16) float lds[2][8192];   // 64 KiB: 2 batch slots
    const int t8 = threadIdx.x;
    const int blk = blockIdx.x;
    const int xcd = blk & 7;
    const int vt = (xcd << 3) | ((blk >> 3) & 7);   // table inout value
    const int pair = blk >> 6;                       // 0..15

    if (blk == 0) {   // zero probs for out_kernel atomics
        float4 z = make_float4(0.f, 0.f, 0.f, 0.f);
        *(float4*)&probs[t8 * 8] = z;
        *(float4*)&probs[t8 * 8 + 4] = z;
    }

    int bb[2], uu[2];
#pragma unroll
    for (int s = 0; s < 2; ++s) {
        int b = pair * 2 + s;
        int fb = 0;
#pragma unroll
        for (int i = 0; i < 6; ++i) fb |= (inputs[b * 6 + i] & 1) << (5 - i);
        bb[s] = b; uu[s] = vt ^ fb;
        const float* src = batch + ((size_t)b << 19) + ((size_t)uu[s] << 13);
#pragma unroll
        for (int k = 0; k < 8; ++k) {
            int i4 = (k * 256 + t8) * 4;
            float4 v = ntload4(&src[i4]);
            *(float4*)&lds[s][SW(i4)] = v;
        }
    }
    float* l0 = lds[0];
    float* l1 = lds[1];

    // float2 table base for this vt (float-indexed; angle x at [2x])
    const float* tb = tab + ((size_t)vt << 12);
#define TN(j) (tb + (size_t)(j) * 262144)
#define BAR __syncthreads()
    BAR;
    // ---- input layer (neurons 0..11, target bit 12-j) ----
    pass_hi2<12, true>(l0, l1, t8, TN(0), TN(1), TN(2), 0,0,0,0,0,0);  BAR;
    pass_hi2<9,  true>(l0, l1, t8, TN(3), TN(4), TN(5), 0,0,0,0,0,0);  BAR;
    pass_hi2<6,  true>(l0, l1, t8, TN(6), TN(7), TN(8), 0,0,0,0,0,0);  BAR;
    pass_lo2<true>(l0, l1, t8, TN(9), TN(10), TN(11), 0,0,0,0,0,0);    BAR;

#pragma unroll 1
    for (int st2 = 0; st2 < 3; ++st2) {
        const float* wu = w_u + st2 * 12;
        float c0, s0, c1, s1, c2, s2;
        sincosf(wu[0], &s0, &c0); sincosf(wu[1], &s1, &c1); sincosf(wu[2], &s2, &c2);
        pass_hi2<12, false>(l0, l1, t8, 0,0,0, c0,s0, c1,s1, c2,s2);   BAR;
        sincosf(wu[3], &s0, &c0); sincosf(wu[4], &s1, &c1); sincosf(wu[5], &s2, &c2);
        pass_hi2<9, false>(l0, l1, t8, 0,0,0, c0,s0, c1,s1, c2,s2);    BAR;
        sincosf(wu[6], &s0, &c0); sincosf(wu[7], &s1, &c1); sincosf(wu[8], &s2, &c2);
        pass_hi2<6, false>(l0, l1, t8, 0,0,0, c0,s0, c1,s1, c2,s2);    BAR;
        sincosf(wu[9], &s0, &c0); sincosf(wu[10], &s1, &c1); sincosf(wu[11], &s2, &c2);
        pass_lo2<false>(l0, l1, t8, 0,0,0, c0,s0, c1,s1, c2,s2);       BAR;

        const int nb = 12 + st2 * 12;
        pass_hi2<12, true>(l0, l1, t8, TN(nb+0), TN(nb+1), TN(nb+2), 0,0,0,0,0,0); BAR;
        pass_hi2<9,  true>(l0, l1, t8, TN(nb+3), TN(nb+4), TN(nb+5), 0,0,0,0,0,0); BAR;
        pass_hi2<6,  true>(l0, l1, t8, TN(nb+6), TN(nb+7), TN(nb+8), 0,0,0,0,0,0); BAR;
        pass_lo2<true>(l0, l1, t8, TN(nb+9), TN(nb+10), TN(nb+11), 0,0,0,0,0,0);   BAR;
    }
#undef TN
#undef BAR

#pragma unroll
    for (int s = 0; s < 2; ++s) {
        float* dst = psi + ((size_t)bb[s] << 19) + ((size_t)uu[s] << 13);
#pragma unroll
        for (int k = 0; k < 8; ++k) {
            int i4 = (k * 256 + t8) * 4;
            float4 v = *(const float4*)&lds[s][SW(i4)];
            ntstore4(&dst[i4], v);
        }
    }
}

// ============================ K3: output layer + probs ============================
// Tile 64 k x 256 cols through LDS. After a[64] extraction the tile in LDS is
// dead (the whole tile lives in registers across the block) -> reuse ts for
// table staging: 3 phases x {coalesced copy of 2 transposed tables (64 KiB),
// butterfly stages 2p,2p+1 reading LDS}. Butterfly LDS reads: lane pairs
// broadcast, 32 distinct addrs on 16 even banks = 2-way conflict (free).
__global__ __launch_bounds__(256, 2) void out_kernel(
    const float* __restrict__ tab, float* __restrict__ psi,
    float* __restrict__ probs)
{
    __shared__ __align__(16) float ts[16384];   // 64 KiB tile / table buffer
    const int tid = threadIdx.x;
    const int lane = tid & 63;
    const int wv = tid >> 6;
    const int b = blockIdx.x >> 5;
    const int c0 = (blockIdx.x & 31) << 8;
    float* gbase = psi + ((size_t)b << 19) + c0;

    // ---- load tile: wave wv rows wv*16..+15, lane l -> cols 4l..4l+3 ----
#pragma unroll
    for (int i = 0; i < 16; ++i) {
        int k = wv * 16 + i;
        float4 v = ntload4(&gbase[((size_t)k << 13) + lane * 4]);
        int f4 = lane ^ (k & 15);
        *(float4*)&ts[k * 256 + f4 * 4] = v;
    }
    __syncthreads();

    // ---- extract column c = tid into registers ----
    float a[64];
#pragma unroll
    for (int k = 0; k < 64; ++k) a[k] = ts[k * 256 + (tid ^ ((k & 15) << 2))];

    // ---- butterfly: 3 phases x (copy 2 tables -> LDS, 2 stages) ----
    const int w12l = tid >> 1;             // local work12 (c>>1 minus base)
    const size_t tbase = (size_t)(c0 >> 1) * 32;   // f2 offset of block chunk
    const float2* tab2 = (const float2*)tab;
    float2* ts2 = (float2*)ts;

#define OSTAGE(J, TSEL) { \
    const int q = 5 - (J); \
    _Pragma("unroll") \
    for (int m = 0; m < 32; ++m) { \
        float2 e = ts2[(TSEL) * 4096 + w12l * 32 + ((m + w12l) & 31)]; \
        const int k0 = ((m >> q) << (q + 1)) | (m & ((1 << q) - 1)); \
        const int k1 = k0 | (1 << q); \
        float A0 = a[k0], A1 = a[k1]; \
        a[k0] = e.x * A0 - e.y * A1; \
        a[k1] = e.y * A0 + e.x * A1; } }

#pragma unroll 1
    for (int p = 0; p < 3; ++p) {
        __syncthreads();   // previous ts use complete
        const float4* g0 = (const float4*)(tab2 + (size_t)(48 + 2 * p) * 131072 + tbase);
        const float4* g1 = (const float4*)(tab2 + (size_t)(49 + 2 * p) * 131072 + tbase);
        float4* d4 = (float4*)ts;
#pragma unroll 4
        for (int it = 0; it < 8; ++it) {
            d4[it * 256 + tid]        = g0[it * 256 + tid];
            d4[2048 + it * 256 + tid] = g1[it * 256 + tid];
        }
        __syncthreads();
        switch (p) {
            case 0: OSTAGE(0, 0) OSTAGE(1, 1) break;
            case 1: OSTAGE(2, 0) OSTAGE(3, 1) break;
            default: OSTAGE(4, 0) OSTAGE(5, 1) break;
        }
    }
#undef OSTAGE

    // ---- write back tile ----
    __syncthreads();
#pragma unroll
    for (int k = 0; k < 64; ++k) ts[k * 256 + (tid ^ ((k & 15) << 2))] = a[k];
    __syncthreads();

#pragma unroll
    for (int i = 0; i < 16; ++i) {
        int k = wv * 16 + i;
        int f4 = lane ^ (k & 15);
        float4 v = *(const float4*)&ts[k * 256 + f4 * 4];
        ntstore4(&gbase[((size_t)k << 13) + lane * 4], v);
    }

    // ---- probs: thread (seg=tid>>6, k=tid&63) sums 64 cols, rotated start ----
    const int k6 = tid & 63, seg = tid >> 6;
    float p = 0.f;
#pragma unroll
    for (int j = 0; j < 64; ++j) {
        int c = seg * 64 + ((j + k6) & 63);
        float v = ts[k6 * 256 + (c ^ ((k6 & 15) << 2))];
        p += v * v;
    }
    atomicAdd(&probs[b * 64 + k6], p);
}

// ============================ launch ============================
extern "C" void kernel_launch(void* const* d_in, const int* in_sizes, int n_in,
                              void* d_out, int out_size, void* d_ws, size_t ws_size,
                              hipStream_t stream)
{
    const float* batch  = (const float*)d_in[0];
    const float* w_in1  = (const float*)d_in[1];
    const float* w_in2  = (const float*)d_in[2];
    const float* w_u    = (const float*)d_in[3];
    const float* w_k1   = (const float*)d_in[4];
    const float* w_k2   = (const float*)d_in[5];
    const float* w_out1 = (const float*)d_in[6];
    const float* w_out2 = (const float*)d_in[7];
    const int*   inputs = (const int*)d_in[8];
    float* probs = (float*)d_out;
    float* psi   = (float*)d_out + 2048;      // 32*64 probs, then 32*2^19 psi
    float* tab   = (float*)d_ws;              // 54 tables x 1 MiB float2 = 54 MiB

    tables_kernel<<<dim3(64, 54), 256, 0, stream>>>(w_in1, w_in2, w_k1, w_k2,
                                                    w_out1, w_out2, tab);
    main_kernel<<<1024, 256, 0, stream>>>(batch, w_u, inputs, tab, psi, probs);
    out_kernel<<<1024, 256, 0, stream>>>(tab, psi, probs);
}

// Round 7
// 338.193 us; speedup vs baseline: 1.1072x; 1.1072x over previous
//
#include <hip/hip_runtime.h>
#include <math.h>

// RVQECell on MI355X.
// State: [B=32][2^19] fp32. Lane l <-> state bit (18-l). inout = bits 13..18,
// work = bits 1..12, ancilla = bit 0 (spectator).
//
// R12 (vs R11 @ 374 us, main=154; R10 @ 328, main=154):
//  R11 post-mortem: residual 174 -> 220. Self-diagnosis: R11 moved the
//  out-table strided access from out_kernel READS to tables_kernel WRITES
//  (8 B per lane at 256 B stride = 64 segments/wave-store, ~+46 us). The
//  transpose is free if done by RE-INDEXING which thread computes which
//  entry instead of permuting the store address:
//   (a) tables_kernel n>=48: thread owns STORAGE index s=(hi<<8)|tid;
//       derive w12=s>>5, m=(s-w12)&31, x=(m<<12)|w12; evaluate phi(x) from
//       all 17 bits directly (153 FMA + sincos; only 786K entries ~ 2 us).
//       Stores fully coalesced in the transposed+swizzled layout.
//   (b) tables_kernel n<48: exact R10 hoisted path (proven inside 174 us).
//   (c) out_kernel: R11's LDS-staged version kept (coalesced chunk reads).
//   (d) main_kernel untouched (control; 154 us).
//  Discriminator: total ~300-320 -> write-pattern was it; >=360 -> R11's
//  out_kernel is the regression, revert it next.

#define BIAS_F 1.57079632679489662f

typedef float v4f __attribute__((ext_vector_type(4)));

__device__ __forceinline__ float4 ntload4(const float* p) {
    v4f v = __builtin_nontemporal_load((const v4f*)p);
    return make_float4(v.x, v.y, v.z, v.w);
}
__device__ __forceinline__ void ntstore4(float* p, float4 f) {
    v4f v = {f.x, f.y, f.z, f.w};
    __builtin_nontemporal_store(v, (v4f*)p);
}

// ---- LDS bank swizzle: fold bits 7..5 into 4..2 (keeps float4 contiguity) ----
__device__ __forceinline__ int SW(int i) { return i ^ ((i >> 3) & 0x1C); }
__device__ __forceinline__ float4 ldsld4(const float* st, int i) {
    return *(const float4*)&st[SW(i)];
}
__device__ __forceinline__ void ldsst4(float* st, int i, float4 v) {
    *(float4*)&st[SW(i)] = v;
}

#define LD2(p) (*(const float2*)(p))
#define LD4(p) (*(const float4*)(p))

// rotation on pairs (A.k, B.k); e = (c01,s01,c23,s23); .x/.y share angle (bit0)
__device__ __forceinline__ void rot4(float4& A, float4& B, float4 e) {
    float ax = A.x, ay = A.y, az = A.z, aw = A.w;
    A.x = e.x * ax - e.y * B.x;  B.x = e.y * ax + e.x * B.x;
    A.y = e.x * ay - e.y * B.y;  B.y = e.y * ay + e.x * B.y;
    A.z = e.z * az - e.w * B.z;  B.z = e.w * az + e.z * B.z;
    A.w = e.z * aw - e.w * B.w;  B.w = e.w * aw + e.z * B.w;
}
// rotation within a quad: pairs (x,z),(y,w)  (target = amp bit 1)
__device__ __forceinline__ void rotq(float4& P, float c, float s) {
    float px = P.x, py = P.y;
    P.x = c * px - s * P.z;  P.z = s * px + c * P.z;
    P.y = c * py - s * P.w;  P.w = s * py + c * P.w;
}

// Table layout (float2 units, tab2 = (float2*)tab):
//  n = 0..47 (main):   tab2[n*131072 + (hi<<8|tid)] = {cos, sin}
//  n = 48..53 (out):   transposed+pre-swizzled:
//                      tab2[n*131072 + w12*32 + ((m + w12)&31)]
//                      where m = x>>12 (5 inout-control bits), w12 = x&4095.
//                      Written COALESCED by storage-indexed threads.

// ============================ K1: tables ============================
__global__ __launch_bounds__(256) void tables_kernel(
    const float* __restrict__ w_in1, const float* __restrict__ w_in2,
    const float* __restrict__ w_k1,  const float* __restrict__ w_k2,
    const float* __restrict__ w_out1, const float* __restrict__ w_out2,
    float* __restrict__ tab)
{
    const int n = blockIdx.y;
    const int hi = blockIdx.x;       // n<48: x bits 16..8.  n>=48: storage hi.
    const int tid = threadIdx.x;
    const float* th1;
    const float* th2;
    if (n < 12)      { th1 = w_in1 + n * 17;         th2 = w_in2 + n * 289; }
    else if (n < 48) { th1 = w_k1 + (n - 12) * 17;   th2 = w_k2 + (n - 12) * 289; }
    else             { th1 = w_out1 + (n - 48) * 17; th2 = w_out2 + (n - 48) * 289; }

    float phi;
    size_t idx;
    if (n < 48) {
        // ---- hoisted path (hi wave-uniform): phi_hi + cross coeffs C[a] ----
        float phi_hi = BIAS_F;
        float C[8];
#pragma unroll
        for (int a = 0; a < 8; ++a) C[a] = th1[9 + a];
#pragma unroll
        for (int i = 0; i < 9; ++i) {
            if ((hi >> (8 - i)) & 1) {
                float acc = th1[i];
#pragma unroll
                for (int j = i + 1; j < 9; ++j)
                    if ((hi >> (8 - j)) & 1) acc += th2[i * 17 + j];
                phi_hi += acc;
#pragma unroll
                for (int a = 0; a < 8; ++a) C[a] += th2[i * 17 + 9 + a];
            }
        }
        float bt[8];
#pragma unroll
        for (int j = 0; j < 8; ++j) bt[j] = (float)((tid >> (7 - j)) & 1);
        phi = phi_hi;
#pragma unroll
        for (int a = 0; a < 8; ++a) {
            float acc = C[a];
#pragma unroll
            for (int b2 = a + 1; b2 < 8; ++b2) acc += bt[b2] * th2[(9 + a) * 17 + 9 + b2];
            phi += bt[a] * acc;
        }
        idx = (size_t)n * 131072 + (size_t)((hi << 8) | tid);
    } else {
        // ---- storage-indexed transposed path: coalesced writes ----
        const int s = (hi << 8) | tid;            // storage index
        const int w12 = s >> 5;
        const int m = (s - w12) & 31;             // inverse of swizzle
        // x = (m<<12) | w12; bits MSB-first: bb[i] = bit (16-i) of x
        float bb[17];
#pragma unroll
        for (int i = 0; i < 5; ++i)  bb[i] = (float)((m >> (4 - i)) & 1);
#pragma unroll
        for (int t = 0; t < 12; ++t) bb[5 + t] = (float)((w12 >> (11 - t)) & 1);
        phi = BIAS_F;
#pragma unroll
        for (int i = 0; i < 17; ++i) {
            float acc = th1[i];
#pragma unroll
            for (int j = i + 1; j < 17; ++j) acc += bb[j] * th2[i * 17 + j];
            phi += bb[i] * acc;
        }
        idx = (size_t)n * 131072 + (size_t)s;
    }

    float sp, cp;
    sincosf(phi, &sp, &cp);
    float c2 = cp * cp, s2 = sp * sp;
    float d = c2 * c2 + s2 * s2;           // >= 0.25 always
    float r = rsqrtf(d);
    r = r * (1.5f - 0.5f * d * r * r);     // one Newton step
    ((float2*)tab)[idx] = make_float2(c2 * r, s2 * r);
}

// ============================ K2: main fused ============================
// High pass, targets {PA,PA-1,PA-2}; unpacked (c,s) table regs (12 float4)
// loaded once, reused for both batch slots. t* point at float2 data
// (float-indexed: angle x lives at [2x]).
template <int PA, bool NEUR>
__device__ __forceinline__ void pass_hi2(float* l0, float* l1, int t8,
    const float* tA, const float* tB, const float* tC,
    float cA, float sA, float cB, float sB, float cC, float sC)
{
    const int lowb = PA - 4;
    const int low = t8 & ((1 << lowb) - 1);
    const int high = t8 >> lowb;
    const int i0 = (high << (PA + 1)) | (low << 2);
    const int x0 = (high << (PA - 1)) | (low << 1);
    const int oa = 1 << PA, ob = oa >> 1, oc = oa >> 2;
    const int dhi = oa >> 2, dlo = oa >> 3;
    float4 ea00, ea01, ea10, ea11, eb00, eb01, eb10, eb11, ec00, ec01, ec10, ec11;
    if (NEUR) {
        ea00 = LD4(&tA[2 * x0]);            ea01 = LD4(&tA[2 * (x0 + dlo)]);
        ea10 = LD4(&tA[2 * (x0 + dhi)]);    ea11 = LD4(&tA[2 * (x0 + dhi + dlo)]);
        eb00 = LD4(&tB[2 * x0]);            eb01 = LD4(&tB[2 * (x0 + dlo)]);
        eb10 = LD4(&tB[2 * (x0 + dhi)]);    eb11 = LD4(&tB[2 * (x0 + dhi + dlo)]);
        ec00 = LD4(&tC[2 * x0]);            ec01 = LD4(&tC[2 * (x0 + dlo)]);
        ec10 = LD4(&tC[2 * (x0 + dhi)]);    ec11 = LD4(&tC[2 * (x0 + dhi + dlo)]);
    } else {
        ea00 = ea01 = ea10 = ea11 = make_float4(cA, sA, cA, sA);
        eb00 = eb01 = eb10 = eb11 = make_float4(cB, sB, cB, sB);
        ec00 = ec01 = ec10 = ec11 = make_float4(cC, sC, cC, sC);
    }
#pragma unroll
    for (int s = 0; s < 2; ++s) {
        float* sl = (s == 0) ? l0 : l1;
        float4 Q000 = ldsld4(sl, i0),            Q001 = ldsld4(sl, i0 + oc);
        float4 Q010 = ldsld4(sl, i0 + ob),       Q011 = ldsld4(sl, i0 + ob + oc);
        float4 Q100 = ldsld4(sl, i0 + oa),       Q101 = ldsld4(sl, i0 + oa + oc);
        float4 Q110 = ldsld4(sl, i0 + oa + ob),  Q111 = ldsld4(sl, i0 + oa + ob + oc);
        // target PA
        rot4(Q000, Q100, ea00); rot4(Q001, Q101, ea01);
        rot4(Q010, Q110, ea10); rot4(Q011, Q111, ea11);
        // target PA-1
        rot4(Q000, Q010, eb00); rot4(Q001, Q011, eb01);
        rot4(Q100, Q110, eb10); rot4(Q101, Q111, eb11);
        // target PA-2
        rot4(Q000, Q001, ec00); rot4(Q010, Q011, ec01);
        rot4(Q100, Q101, ec10); rot4(Q110, Q111, ec11);
        ldsst4(sl, i0, Q000);            ldsst4(sl, i0 + oc, Q001);
        ldsst4(sl, i0 + ob, Q010);       ldsst4(sl, i0 + ob + oc, Q011);
        ldsst4(sl, i0 + oa, Q100);       ldsst4(sl, i0 + oa + oc, Q101);
        ldsst4(sl, i0 + oa + ob, Q110);  ldsst4(sl, i0 + oa + ob + oc, Q111);
    }
}

// Low pass, targets {3,2,1}. Thread owns amps i0..i0+31 (8 angles x0..x0+7).
template <bool NEUR>
__device__ __forceinline__ void pass_lo2(float* l0, float* l1, int t8,
    const float* tA, const float* tB, const float* tC,
    float cA, float sA, float cB, float sB, float cC, float sC)
{
    const int i0 = t8 << 5, x0 = t8 << 3;
    float4 ea0, ea1, ea2, ea3, eb0, eb1, eb2, eb3, ec0, ec1, ec2, ec3;
    if (NEUR) {
        ea0 = LD4(&tA[2 * x0]);      ea1 = LD4(&tA[2 * x0 + 4]);
        ea2 = LD4(&tA[2 * x0 + 8]);  ea3 = LD4(&tA[2 * x0 + 12]);
        eb0 = LD4(&tB[2 * x0]);      eb1 = LD4(&tB[2 * x0 + 4]);
        eb2 = LD4(&tB[2 * x0 + 8]);  eb3 = LD4(&tB[2 * x0 + 12]);
        ec0 = LD4(&tC[2 * x0]);      ec1 = LD4(&tC[2 * x0 + 4]);
        ec2 = LD4(&tC[2 * x0 + 8]);  ec3 = LD4(&tC[2 * x0 + 12]);
    } else {
        ea0 = ea1 = ea2 = ea3 = make_float4(cA, sA, cA, sA);
        eb0 = eb1 = eb2 = eb3 = make_float4(cB, sB, cB, sB);
        ec0 = ec1 = ec2 = ec3 = make_float4(cC, sC, cC, sC);
    }
#pragma unroll
    for (int s = 0; s < 2; ++s) {
        float* sl = (s == 0) ? l0 : l1;
        float4 Q0 = ldsld4(sl, i0),      Q1 = ldsld4(sl, i0 + 4);
        float4 Q2 = ldsld4(sl, i0 + 8),  Q3 = ldsld4(sl, i0 + 12);
        float4 Q4 = ldsld4(sl, i0 + 16), Q5 = ldsld4(sl, i0 + 20);
        float4 Q6 = ldsld4(sl, i0 + 24), Q7 = ldsld4(sl, i0 + 28);
        // target 3: pairs (k, k+2)
        rot4(Q0, Q2, ea0); rot4(Q1, Q3, ea1); rot4(Q4, Q6, ea2); rot4(Q5, Q7, ea3);
        // target 2: pairs (k, k+1)
        rot4(Q0, Q1, eb0); rot4(Q2, Q3, eb1); rot4(Q4, Q5, eb2); rot4(Q6, Q7, eb3);
        // target 1: in-quad
        rotq(Q0, ec0.x, ec0.y); rotq(Q1, ec0.z, ec0.w);
        rotq(Q2, ec1.x, ec1.y); rotq(Q3, ec1.z, ec1.w);
        rotq(Q4, ec2.x, ec2.y); rotq(Q5, ec2.z, ec2.w);
        rotq(Q6, ec3.x, ec3.y); rotq(Q7, ec3.z, ec3.w);
        ldsst4(sl, i0, Q0);      ldsst4(sl, i0 + 4, Q1);
        ldsst4(sl, i0 + 8, Q2);  ldsst4(sl, i0 + 12, Q3);
        ldsst4(sl, i0 + 16, Q4); ldsst4(sl, i0 + 20, Q5);
        ldsst4(sl, i0 + 24, Q6); ldsst4(sl, i0 + 28, Q7);
    }
}

__global__ __launch_bounds__(256, 2) void main_kernel(
    const float* __restrict__ batch, const float* __restrict__ w_u,
    const int* __restrict__ inputs, const float* __restrict__ tab,
    float* __restrict__ psi, float* __restrict__ probs)
{
    __shared__ __align__(16) float lds[2][8192];   // 64 KiB: 2 batch slots
    const int t8 = threadIdx.x;
    const int blk = blockIdx.x;
    const int xcd = blk & 7;
    const int vt = (xcd << 3) | ((blk >> 3) & 7);   // table inout value
    const int pair = blk >> 6;                       // 0..15

    if (blk == 0) {   // zero probs for out_kernel atomics
        float4 z = make_float4(0.f, 0.f, 0.f, 0.f);
        *(float4*)&probs[t8 * 8] = z;
        *(float4*)&probs[t8 * 8 + 4] = z;
    }

    int bb[2], uu[2];
#pragma unroll
    for (int s = 0; s < 2; ++s) {
        int b = pair * 2 + s;
        int fb = 0;
#pragma unroll
        for (int i = 0; i < 6; ++i) fb |= (inputs[b * 6 + i] & 1) << (5 - i);
        bb[s] = b; uu[s] = vt ^ fb;
        const float* src = batch + ((size_t)b << 19) + ((size_t)uu[s] << 13);
#pragma unroll
        for (int k = 0; k < 8; ++k) {
            int i4 = (k * 256 + t8) * 4;
            float4 v = ntload4(&src[i4]);
            *(float4*)&lds[s][SW(i4)] = v;
        }
    }
    float* l0 = lds[0];
    float* l1 = lds[1];

    // float2 table base for this vt (float-indexed; angle x at [2x])
    const float* tb = tab + ((size_t)vt << 12);
#define TN(j) (tb + (size_t)(j) * 262144)
#define BAR __syncthreads()
    BAR;
    // ---- input layer (neurons 0..11, target bit 12-j) ----
    pass_hi2<12, true>(l0, l1, t8, TN(0), TN(1), TN(2), 0,0,0,0,0,0);  BAR;
    pass_hi2<9,  true>(l0, l1, t8, TN(3), TN(4), TN(5), 0,0,0,0,0,0);  BAR;
    pass_hi2<6,  true>(l0, l1, t8, TN(6), TN(7), TN(8), 0,0,0,0,0,0);  BAR;
    pass_lo2<true>(l0, l1, t8, TN(9), TN(10), TN(11), 0,0,0,0,0,0);    BAR;

#pragma unroll 1
    for (int st2 = 0; st2 < 3; ++st2) {
        const float* wu = w_u + st2 * 12;
        float c0, s0, c1, s1, c2, s2;
        sincosf(wu[0], &s0, &c0); sincosf(wu[1], &s1, &c1); sincosf(wu[2], &s2, &c2);
        pass_hi2<12, false>(l0, l1, t8, 0,0,0, c0,s0, c1,s1, c2,s2);   BAR;
        sincosf(wu[3], &s0, &c0); sincosf(wu[4], &s1, &c1); sincosf(wu[5], &s2, &c2);
        pass_hi2<9, false>(l0, l1, t8, 0,0,0, c0,s0, c1,s1, c2,s2);    BAR;
        sincosf(wu[6], &s0, &c0); sincosf(wu[7], &s1, &c1); sincosf(wu[8], &s2, &c2);
        pass_hi2<6, false>(l0, l1, t8, 0,0,0, c0,s0, c1,s1, c2,s2);    BAR;
        sincosf(wu[9], &s0, &c0); sincosf(wu[10], &s1, &c1); sincosf(wu[11], &s2, &c2);
        pass_lo2<false>(l0, l1, t8, 0,0,0, c0,s0, c1,s1, c2,s2);       BAR;

        const int nb = 12 + st2 * 12;
        pass_hi2<12, true>(l0, l1, t8, TN(nb+0), TN(nb+1), TN(nb+2), 0,0,0,0,0,0); BAR;
        pass_hi2<9,  true>(l0, l1, t8, TN(nb+3), TN(nb+4), TN(nb+5), 0,0,0,0,0,0); BAR;
        pass_hi2<6,  true>(l0, l1, t8, TN(nb+6), TN(nb+7), TN(nb+8), 0,0,0,0,0,0); BAR;
        pass_lo2<true>(l0, l1, t8, TN(nb+9), TN(nb+10), TN(nb+11), 0,0,0,0,0,0);   BAR;
    }
#undef TN
#undef BAR

#pragma unroll
    for (int s = 0; s < 2; ++s) {
        float* dst = psi + ((size_t)bb[s] << 19) + ((size_t)uu[s] << 13);
#pragma unroll
        for (int k = 0; k < 8; ++k) {
            int i4 = (k * 256 + t8) * 4;
            float4 v = *(const float4*)&lds[s][SW(i4)];
            ntstore4(&dst[i4], v);
        }
    }
}

// ============================ K3: output layer + probs ============================
// Tile 64 k x 256 cols through LDS. After a[64] extraction the tile in LDS is
// dead -> reuse ts for table staging: 3 phases x {coalesced copy of 2
// transposed tables (64 KiB), butterfly stages 2p,2p+1 reading LDS}.
__global__ __launch_bounds__(256, 2) void out_kernel(
    const float* __restrict__ tab, float* __restrict__ psi,
    float* __restrict__ probs)
{
    __shared__ __align__(16) float ts[16384];   // 64 KiB tile / table buffer
    const int tid = threadIdx.x;
    const int lane = tid & 63;
    const int wv = tid >> 6;
    const int b = blockIdx.x >> 5;
    const int c0 = (blockIdx.x & 31) << 8;
    float* gbase = psi + ((size_t)b << 19) + c0;

    // ---- load tile: wave wv rows wv*16..+15, lane l -> cols 4l..4l+3 ----
#pragma unroll
    for (int i = 0; i < 16; ++i) {
        int k = wv * 16 + i;
        float4 v = ntload4(&gbase[((size_t)k << 13) + lane * 4]);
        int f4 = lane ^ (k & 15);
        *(float4*)&ts[k * 256 + f4 * 4] = v;
    }
    __syncthreads();

    // ---- extract column c = tid into registers ----
    float a[64];
#pragma unroll
    for (int k = 0; k < 64; ++k) a[k] = ts[k * 256 + (tid ^ ((k & 15) << 2))];

    // ---- butterfly: 3 phases x (copy 2 tables -> LDS, 2 stages) ----
    const int w12l = tid >> 1;             // local work12 (c>>1 minus base)
    const size_t tbase = (size_t)(c0 >> 1) * 32;   // f2 offset of block chunk
    const float2* tab2 = (const float2*)tab;
    float2* ts2 = (float2*)ts;

#define OSTAGE(J, TSEL) { \
    const int q = 5 - (J); \
    _Pragma("unroll") \
    for (int m = 0; m < 32; ++m) { \
        float2 e = ts2[(TSEL) * 4096 + w12l * 32 + ((m + w12l) & 31)]; \
        const int k0 = ((m >> q) << (q + 1)) | (m & ((1 << q) - 1)); \
        const int k1 = k0 | (1 << q); \
        float A0 = a[k0], A1 = a[k1]; \
        a[k0] = e.x * A0 - e.y * A1; \
        a[k1] = e.y * A0 + e.x * A1; } }

#pragma unroll 1
    for (int p = 0; p < 3; ++p) {
        __syncthreads();   // previous ts use complete
        const float4* g0 = (const float4*)(tab2 + (size_t)(48 + 2 * p) * 131072 + tbase);
        const float4* g1 = (const float4*)(tab2 + (size_t)(49 + 2 * p) * 131072 + tbase);
        float4* d4 = (float4*)ts;
#pragma unroll 4
        for (int it = 0; it < 8; ++it) {
            d4[it * 256 + tid]        = g0[it * 256 + tid];
            d4[2048 + it * 256 + tid] = g1[it * 256 + tid];
        }
        __syncthreads();
        switch (p) {
            case 0: OSTAGE(0, 0) OSTAGE(1, 1) break;
            case 1: OSTAGE(2, 0) OSTAGE(3, 1) break;
            default: OSTAGE(4, 0) OSTAGE(5, 1) break;
        }
    }
#undef OSTAGE

    // ---- write back tile ----
    __syncthreads();
#pragma unroll
    for (int k = 0; k < 64; ++k) ts[k * 256 + (tid ^ ((k & 15) << 2))] = a[k];
    __syncthreads();

#pragma unroll
    for (int i = 0; i < 16; ++i) {
        int k = wv * 16 + i;
        int f4 = lane ^ (k & 15);
        float4 v = *(const float4*)&ts[k * 256 + f4 * 4];
        ntstore4(&gbase[((size_t)k << 13) + lane * 4], v);
    }

    // ---- probs: thread (seg=tid>>6, k=tid&63) sums 64 cols, rotated start ----
    const int k6 = tid & 63, seg = tid >> 6;
    float p = 0.f;
#pragma unroll
    for (int j = 0; j < 64; ++j) {
        int c = seg * 64 + ((j + k6) & 63);
        float v = ts[k6 * 256 + (c ^ ((k6 & 15) << 2))];
        p += v * v;
    }
    atomicAdd(&probs[b * 64 + k6], p);
}

// ============================ launch ============================
extern "C" void kernel_launch(void* const* d_in, const int* in_sizes, int n_in,
                              void* d_out, int out_size, void* d_ws, size_t ws_size,
                              hipStream_t stream)
{
    const float* batch  = (const float*)d_in[0];
    const float* w_in1  = (const float*)d_in[1];
    const float* w_in2  = (const float*)d_in[2];
    const float* w_u    = (const float*)d_in[3];
    const float* w_k1   = (const float*)d_in[4];
    const float* w_k2   = (const float*)d_in[5];
    const float* w_out1 = (const float*)d_in[6];
    const float* w_out2 = (const float*)d_in[7];
    const int*   inputs = (const int*)d_in[8];
    float* probs = (float*)d_out;
    float* psi   = (float*)d_out + 2048;      // 32*64 probs, then 32*2^19 psi
    float* tab   = (float*)d_ws;              // 54 tables x 1 MiB float2 = 54 MiB

    tables_kernel<<<dim3(512, 54), 256, 0, stream>>>(w_in1, w_in2, w_k1, w_k2,
                                                     w_out1, w_out2, tab);
    main_kernel<<<1024, 256, 0, stream>>>(batch, w_u, inputs, tab, psi, probs);
    out_kernel<<<1024, 256, 0, stream>>>(tab, psi, probs);
}

// Round 9
// 337.797 us; speedup vs baseline: 1.1085x; 1.0012x over previous
//
#include <hip/hip_runtime.h>
#include <math.h>

// RVQECell on MI355X.
// State: [B=32][2^19] fp32. Lane l <-> state bit (18-l). inout = bits 13..18,
// work = bits 1..12, ancilla = bit 0 (spectator).
//
// R14 = R13 resubmitted verbatim (R13 bench died with "MI355X container
// failed twice" = infra/acquisition flake, not a kernel fault; no compile
// or correctness error reported, and the diff contained nothing
// graph-capture-hostile: two plain 512-block dispatches, scalar arg).
//
// R13 rationale (vs R12 @ 338, R10 @ 328 = best):
//  Three rounds of blind surgery on the ~174-182 us residual (tables+out)
//  produced: R10 174 / R11 220 / R12 182. The two out_kernel forms measure
//  within 8 us -> out's table loads were never the bottleneck. Floor math
//  (tables ~25 + out ~40) still doesn't reach 174. Stop guessing:
//  MEASURE. main_kernel split into two 512-block dispatches (batches 0-15,
//  16-31). 512 blocks = 2/CU x 256 CU full residency (identical per-block
//  work, same vt->XCD table locality) -> each half ~77 us. The top-5
//  duration threshold drops 154 -> 77 us: tables_kernel / out_kernel surface
//  WITH COUNTERS iff they exceed ~77 us. If neither appears -> both < 77,
//  residual is launch overhead -> next = fusion.
//  All else = exact R10 source (best total).

#define BIAS_F 1.57079632679489662f

typedef float v4f __attribute__((ext_vector_type(4)));

__device__ __forceinline__ float4 ntload4(const float* p) {
    v4f v = __builtin_nontemporal_load((const v4f*)p);
    return make_float4(v.x, v.y, v.z, v.w);
}
__device__ __forceinline__ void ntstore4(float* p, float4 f) {
    v4f v = {f.x, f.y, f.z, f.w};
    __builtin_nontemporal_store(v, (v4f*)p);
}

// ---- LDS bank swizzle: fold bits 7..5 into 4..2 (keeps float4 contiguity) ----
__device__ __forceinline__ int SW(int i) { return i ^ ((i >> 3) & 0x1C); }
__device__ __forceinline__ float4 ldsld4(const float* st, int i) {
    return *(const float4*)&st[SW(i)];
}
__device__ __forceinline__ void ldsst4(float* st, int i, float4 v) {
    *(float4*)&st[SW(i)] = v;
}

#define LD2(p) (*(const float2*)(p))
#define LD4(p) (*(const float4*)(p))

// rotation on pairs (A.k, B.k); e = (c01,s01,c23,s23); .x/.y share angle (bit0)
__device__ __forceinline__ void rot4(float4& A, float4& B, float4 e) {
    float ax = A.x, ay = A.y, az = A.z, aw = A.w;
    A.x = e.x * ax - e.y * B.x;  B.x = e.y * ax + e.x * B.x;
    A.y = e.x * ay - e.y * B.y;  B.y = e.y * ay + e.x * B.y;
    A.z = e.z * az - e.w * B.z;  B.z = e.w * az + e.z * B.z;
    A.w = e.z * aw - e.w * B.w;  B.w = e.w * aw + e.z * B.w;
}
// rotation within a quad: pairs (x,z),(y,w)  (target = amp bit 1)
__device__ __forceinline__ void rotq(float4& P, float c, float s) {
    float px = P.x, py = P.y;
    P.x = c * px - s * P.z;  P.z = s * px + c * P.z;
    P.y = c * py - s * P.w;  P.w = s * py + c * P.w;
}

// Table layout: float2 tab2[n * 131072 + x] = {cos a, sin a}, n = 0..53.
// n 0..47 = main-layer neurons, 48..53 = out-layer neurons. 54 MiB total.

// ============================ K1: tables ============================
__global__ __launch_bounds__(256) void tables_kernel(
    const float* __restrict__ w_in1, const float* __restrict__ w_in2,
    const float* __restrict__ w_k1,  const float* __restrict__ w_k2,
    const float* __restrict__ w_out1, const float* __restrict__ w_out2,
    float* __restrict__ tab)
{
    const int n = blockIdx.y;
    const int hi = blockIdx.x;       // x bits 16..8 (wave-uniform)
    const int tid = threadIdx.x;     // x bits 7..0
    const float* th1;
    const float* th2;
    if (n < 12)      { th1 = w_in1 + n * 17;         th2 = w_in2 + n * 289; }
    else if (n < 48) { th1 = w_k1 + (n - 12) * 17;   th2 = w_k2 + (n - 12) * 289; }
    else             { th1 = w_out1 + (n - 48) * 17; th2 = w_out2 + (n - 48) * 289; }

    // ---- wave-uniform hi part: phi_hi + cross coefficients C[a] ----
    float phi_hi = BIAS_F;
    float C[8];
#pragma unroll
    for (int a = 0; a < 8; ++a) C[a] = th1[9 + a];
#pragma unroll
    for (int i = 0; i < 9; ++i) {
        if ((hi >> (8 - i)) & 1) {
            float acc = th1[i];
#pragma unroll
            for (int j = i + 1; j < 9; ++j)
                if ((hi >> (8 - j)) & 1) acc += th2[i * 17 + j];
            phi_hi += acc;
#pragma unroll
            for (int a = 0; a < 8; ++a) C[a] += th2[i * 17 + 9 + a];
        }
    }

    // ---- per-thread lo part: 36 FMA ----
    float bt[8];
#pragma unroll
    for (int j = 0; j < 8; ++j) bt[j] = (float)((tid >> (7 - j)) & 1);
    float phi = phi_hi;
#pragma unroll
    for (int a = 0; a < 8; ++a) {
        float acc = C[a];
#pragma unroll
        for (int b2 = a + 1; b2 < 8; ++b2) acc += bt[b2] * th2[(9 + a) * 17 + 9 + b2];
        phi += bt[a] * acc;
    }

    float sp, cp;
    sincosf(phi, &sp, &cp);
    float c2 = cp * cp, s2 = sp * sp;
    float d = c2 * c2 + s2 * s2;           // >= 0.25 always
    float r = rsqrtf(d);
    r = r * (1.5f - 0.5f * d * r * r);     // one Newton step
    float2* dst = (float2*)tab + ((size_t)n * 131072 + (size_t)((hi << 8) | tid));
    *dst = make_float2(c2 * r, s2 * r);    // {cos a, sin a}
}

// ============================ K2: main fused ============================
// High pass, targets {PA,PA-1,PA-2}; unpacked (c,s) table regs (12 float4)
// loaded once, reused for both batch slots. t* point at float2 data
// (float-indexed: angle x lives at [2x]).
template <int PA, bool NEUR>
__device__ __forceinline__ void pass_hi2(float* l0, float* l1, int t8,
    const float* tA, const float* tB, const float* tC,
    float cA, float sA, float cB, float sB, float cC, float sC)
{
    const int lowb = PA - 4;
    const int low = t8 & ((1 << lowb) - 1);
    const int high = t8 >> lowb;
    const int i0 = (high << (PA + 1)) | (low << 2);
    const int x0 = (high << (PA - 1)) | (low << 1);
    const int oa = 1 << PA, ob = oa >> 1, oc = oa >> 2;
    const int dhi = oa >> 2, dlo = oa >> 3;
    float4 ea00, ea01, ea10, ea11, eb00, eb01, eb10, eb11, ec00, ec01, ec10, ec11;
    if (NEUR) {
        ea00 = LD4(&tA[2 * x0]);            ea01 = LD4(&tA[2 * (x0 + dlo)]);
        ea10 = LD4(&tA[2 * (x0 + dhi)]);    ea11 = LD4(&tA[2 * (x0 + dhi + dlo)]);
        eb00 = LD4(&tB[2 * x0]);            eb01 = LD4(&tB[2 * (x0 + dlo)]);
        eb10 = LD4(&tB[2 * (x0 + dhi)]);    eb11 = LD4(&tB[2 * (x0 + dhi + dlo)]);
        ec00 = LD4(&tC[2 * x0]);            ec01 = LD4(&tC[2 * (x0 + dlo)]);
        ec10 = LD4(&tC[2 * (x0 + dhi)]);    ec11 = LD4(&tC[2 * (x0 + dhi + dlo)]);
    } else {
        ea00 = ea01 = ea10 = ea11 = make_float4(cA, sA, cA, sA);
        eb00 = eb01 = eb10 = eb11 = make_float4(cB, sB, cB, sB);
        ec00 = ec01 = ec10 = ec11 = make_float4(cC, sC, cC, sC);
    }
#pragma unroll
    for (int s = 0; s < 2; ++s) {
        float* sl = (s == 0) ? l0 : l1;
        float4 Q000 = ldsld4(sl, i0),            Q001 = ldsld4(sl, i0 + oc);
        float4 Q010 = ldsld4(sl, i0 + ob),       Q011 = ldsld4(sl, i0 + ob + oc);
        float4 Q100 = ldsld4(sl, i0 + oa),       Q101 = ldsld4(sl, i0 + oa + oc);
        float4 Q110 = ldsld4(sl, i0 + oa + ob),  Q111 = ldsld4(sl, i0 + oa + ob + oc);
        // target PA
        rot4(Q000, Q100, ea00); rot4(Q001, Q101, ea01);
        rot4(Q010, Q110, ea10); rot4(Q011, Q111, ea11);
        // target PA-1
        rot4(Q000, Q010, eb00); rot4(Q001, Q011, eb01);
        rot4(Q100, Q110, eb10); rot4(Q101, Q111, eb11);
        // target PA-2
        rot4(Q000, Q001, ec00); rot4(Q010, Q011, ec01);
        rot4(Q100, Q101, ec10); rot4(Q110, Q111, ec11);
        ldsst4(sl, i0, Q000);            ldsst4(sl, i0 + oc, Q001);
        ldsst4(sl, i0 + ob, Q010);       ldsst4(sl, i0 + ob + oc, Q011);
        ldsst4(sl, i0 + oa, Q100);       ldsst4(sl, i0 + oa + oc, Q101);
        ldsst4(sl, i0 + oa + ob, Q110);  ldsst4(sl, i0 + oa + ob + oc, Q111);
    }
}

// Low pass, targets {3,2,1}. Thread owns amps i0..i0+31 (8 angles x0..x0+7).
template <bool NEUR>
__device__ __forceinline__ void pass_lo2(float* l0, float* l1, int t8,
    const float* tA, const float* tB, const float* tC,
    float cA, float sA, float cB, float sB, float cC, float sC)
{
    const int i0 = t8 << 5, x0 = t8 << 3;
    float4 ea0, ea1, ea2, ea3, eb0, eb1, eb2, eb3, ec0, ec1, ec2, ec3;
    if (NEUR) {
        ea0 = LD4(&tA[2 * x0]);      ea1 = LD4(&tA[2 * x0 + 4]);
        ea2 = LD4(&tA[2 * x0 + 8]);  ea3 = LD4(&tA[2 * x0 + 12]);
        eb0 = LD4(&tB[2 * x0]);      eb1 = LD4(&tB[2 * x0 + 4]);
        eb2 = LD4(&tB[2 * x0 + 8]);  eb3 = LD4(&tB[2 * x0 + 12]);
        ec0 = LD4(&tC[2 * x0]);      ec1 = LD4(&tC[2 * x0 + 4]);
        ec2 = LD4(&tC[2 * x0 + 8]);  ec3 = LD4(&tC[2 * x0 + 12]);
    } else {
        ea0 = ea1 = ea2 = ea3 = make_float4(cA, sA, cA, sA);
        eb0 = eb1 = eb2 = eb3 = make_float4(cB, sB, cB, sB);
        ec0 = ec1 = ec2 = ec3 = make_float4(cC, sC, cC, sC);
    }
#pragma unroll
    for (int s = 0; s < 2; ++s) {
        float* sl = (s == 0) ? l0 : l1;
        float4 Q0 = ldsld4(sl, i0),      Q1 = ldsld4(sl, i0 + 4);
        float4 Q2 = ldsld4(sl, i0 + 8),  Q3 = ldsld4(sl, i0 + 12);
        float4 Q4 = ldsld4(sl, i0 + 16), Q5 = ldsld4(sl, i0 + 20);
        float4 Q6 = ldsld4(sl, i0 + 24), Q7 = ldsld4(sl, i0 + 28);
        // target 3: pairs (k, k+2)
        rot4(Q0, Q2, ea0); rot4(Q1, Q3, ea1); rot4(Q4, Q6, ea2); rot4(Q5, Q7, ea3);
        // target 2: pairs (k, k+1)
        rot4(Q0, Q1, eb0); rot4(Q2, Q3, eb1); rot4(Q4, Q5, eb2); rot4(Q6, Q7, eb3);
        // target 1: in-quad
        rotq(Q0, ec0.x, ec0.y); rotq(Q1, ec0.z, ec0.w);
        rotq(Q2, ec1.x, ec1.y); rotq(Q3, ec1.z, ec1.w);
        rotq(Q4, ec2.x, ec2.y); rotq(Q5, ec2.z, ec2.w);
        rotq(Q6, ec3.x, ec3.y); rotq(Q7, ec3.z, ec3.w);
        ldsst4(sl, i0, Q0);      ldsst4(sl, i0 + 4, Q1);
        ldsst4(sl, i0 + 8, Q2);  ldsst4(sl, i0 + 12, Q3);
        ldsst4(sl, i0 + 16, Q4); ldsst4(sl, i0 + 20, Q5);
        ldsst4(sl, i0 + 24, Q6); ldsst4(sl, i0 + 28, Q7);
    }
}

// 512 blocks per dispatch (= exactly 2 blocks/CU full residency), batches
// bofs*16 .. bofs*16+15. Two dispatches == one R10 1024-block dispatch.
__global__ __launch_bounds__(256, 2) void main_kernel(
    const float* __restrict__ batch, const float* __restrict__ w_u,
    const int* __restrict__ inputs, const float* __restrict__ tab,
    float* __restrict__ psi, float* __restrict__ probs, int bofs)
{
    __shared__ __align__(16) float lds[2][8192];   // 64 KiB: 2 batch slots
    const int t8 = threadIdx.x;
    const int blk = blockIdx.x;
    const int xcd = blk & 7;
    const int vt = (xcd << 3) | ((blk >> 3) & 7);   // table inout value
    const int pair = (blk >> 6) + bofs * 8;          // 0..15

    if (blk == 0 && bofs == 0) {   // zero probs for out_kernel atomics
        float4 z = make_float4(0.f, 0.f, 0.f, 0.f);
        *(float4*)&probs[t8 * 8] = z;
        *(float4*)&probs[t8 * 8 + 4] = z;
    }

    int bb[2], uu[2];
#pragma unroll
    for (int s = 0; s < 2; ++s) {
        int b = pair * 2 + s;
        int fb = 0;
#pragma unroll
        for (int i = 0; i < 6; ++i) fb |= (inputs[b * 6 + i] & 1) << (5 - i);
        bb[s] = b; uu[s] = vt ^ fb;
        const float* src = batch + ((size_t)b << 19) + ((size_t)uu[s] << 13);
#pragma unroll
        for (int k = 0; k < 8; ++k) {
            int i4 = (k * 256 + t8) * 4;
            float4 v = ntload4(&src[i4]);
            *(float4*)&lds[s][SW(i4)] = v;
        }
    }
    float* l0 = lds[0];
    float* l1 = lds[1];

    // float2 table base for this vt (float-indexed; angle x at [2x])
    const float* tb = tab + ((size_t)vt << 12);
#define TN(j) (tb + (size_t)(j) * 262144)
#define BAR __syncthreads()
    BAR;
    // ---- input layer (neurons 0..11, target bit 12-j) ----
    pass_hi2<12, true>(l0, l1, t8, TN(0), TN(1), TN(2), 0,0,0,0,0,0);  BAR;
    pass_hi2<9,  true>(l0, l1, t8, TN(3), TN(4), TN(5), 0,0,0,0,0,0);  BAR;
    pass_hi2<6,  true>(l0, l1, t8, TN(6), TN(7), TN(8), 0,0,0,0,0,0);  BAR;
    pass_lo2<true>(l0, l1, t8, TN(9), TN(10), TN(11), 0,0,0,0,0,0);    BAR;

#pragma unroll 1
    for (int st2 = 0; st2 < 3; ++st2) {
        const float* wu = w_u + st2 * 12;
        float c0, s0, c1, s1, c2, s2;
        sincosf(wu[0], &s0, &c0); sincosf(wu[1], &s1, &c1); sincosf(wu[2], &s2, &c2);
        pass_hi2<12, false>(l0, l1, t8, 0,0,0, c0,s0, c1,s1, c2,s2);   BAR;
        sincosf(wu[3], &s0, &c0); sincosf(wu[4], &s1, &c1); sincosf(wu[5], &s2, &c2);
        pass_hi2<9, false>(l0, l1, t8, 0,0,0, c0,s0, c1,s1, c2,s2);    BAR;
        sincosf(wu[6], &s0, &c0); sincosf(wu[7], &s1, &c1); sincosf(wu[8], &s2, &c2);
        pass_hi2<6, false>(l0, l1, t8, 0,0,0, c0,s0, c1,s1, c2,s2);    BAR;
        sincosf(wu[9], &s0, &c0); sincosf(wu[10], &s1, &c1); sincosf(wu[11], &s2, &c2);
        pass_lo2<false>(l0, l1, t8, 0,0,0, c0,s0, c1,s1, c2,s2);       BAR;

        const int nb = 12 + st2 * 12;
        pass_hi2<12, true>(l0, l1, t8, TN(nb+0), TN(nb+1), TN(nb+2), 0,0,0,0,0,0); BAR;
        pass_hi2<9,  true>(l0, l1, t8, TN(nb+3), TN(nb+4), TN(nb+5), 0,0,0,0,0,0); BAR;
        pass_hi2<6,  true>(l0, l1, t8, TN(nb+6), TN(nb+7), TN(nb+8), 0,0,0,0,0,0); BAR;
        pass_lo2<true>(l0, l1, t8, TN(nb+9), TN(nb+10), TN(nb+11), 0,0,0,0,0,0);   BAR;
    }
#undef TN
#undef BAR

#pragma unroll
    for (int s = 0; s < 2; ++s) {
        float* dst = psi + ((size_t)bb[s] << 19) + ((size_t)uu[s] << 13);
#pragma unroll
        for (int k = 0; k < 8; ++k) {
            int i4 = (k * 256 + t8) * 4;
            float4 v = *(const float4*)&lds[s][SW(i4)];
            ntstore4(&dst[i4], v);
        }
    }
}

// ============================ K3: output layer + probs ============================
// Tile 64 k x 256 cols through LDS (XOR-swizzled, conflict-free). Tables are
// unpacked float2 -> no dec() in the butterfly chain. ev staged 16-at-a-time
// to bound load hoisting (a[64] + 32 ev regs ~ 110 < 128).
__global__ __launch_bounds__(256, 2) void out_kernel(
    const float* __restrict__ tab, float* __restrict__ psi,
    float* __restrict__ probs)
{
    __shared__ __align__(16) float ts[16384];   // 64 KiB tile
    const int tid = threadIdx.x;
    const int lane = tid & 63;
    const int wv = tid >> 6;
    const int b = blockIdx.x >> 5;
    const int c0 = (blockIdx.x & 31) << 8;
    float* gbase = psi + ((size_t)b << 19) + c0;

    // ---- load: wave wv loads rows wv*16..wv*16+15, lane l -> cols 4l..4l+3 ----
#pragma unroll
    for (int i = 0; i < 16; ++i) {
        int k = wv * 16 + i;
        float4 v = ntload4(&gbase[((size_t)k << 13) + lane * 4]);
        int f4 = lane ^ (k & 15);
        *(float4*)&ts[k * 256 + f4 * 4] = v;
    }
    __syncthreads();

    // ---- column phase: thread owns col c = tid ----
    float a[64];
#pragma unroll
    for (int k = 0; k < 64; ++k) a[k] = ts[k * 256 + (tid ^ ((k & 15) << 2))];
    const int w12 = (c0 | tid) >> 1;

#define OSTAGE(J) { \
    const float* tj = tab + 2u * ((size_t)(48 + (J)) * 131072 + (size_t)w12); \
    _Pragma("unroll") \
    for (int h = 0; h < 2; ++h) { \
        float2 ev[16]; \
        _Pragma("unroll") \
        for (int m = 0; m < 16; ++m) ev[m] = LD2(&tj[(size_t)(h * 16 + m) << 13]); \
        _Pragma("unroll") \
        for (int m = 0; m < 16; ++m) { \
            const int mm = h * 16 + m; \
            const int q = 5 - (J); \
            const int k0 = ((mm >> q) << (q + 1)) | (mm & ((1 << q) - 1)); \
            const int k1 = k0 | (1 << q); \
            float2 e = ev[m]; \
            float A0 = a[k0], A1 = a[k1]; \
            a[k0] = e.x * A0 - e.y * A1; \
            a[k1] = e.y * A0 + e.x * A1; } } }
    OSTAGE(0) OSTAGE(1) OSTAGE(2) OSTAGE(3) OSTAGE(4) OSTAGE(5)
#undef OSTAGE

#pragma unroll
    for (int k = 0; k < 64; ++k) ts[k * 256 + (tid ^ ((k & 15) << 2))] = a[k];
    __syncthreads();

    // ---- store rows back (float4) ----
#pragma unroll
    for (int i = 0; i < 16; ++i) {
        int k = wv * 16 + i;
        int f4 = lane ^ (k & 15);
        float4 v = *(const float4*)&ts[k * 256 + f4 * 4];
        ntstore4(&gbase[((size_t)k << 13) + lane * 4], v);
    }

    // ---- probs: thread (seg=tid>>6, k=tid&63) sums 64 cols, rotated start ----
    const int k6 = tid & 63, seg = tid >> 6;
    float p = 0.f;
#pragma unroll
    for (int j = 0; j < 64; ++j) {
        int c = seg * 64 + ((j + k6) & 63);
        float v = ts[k6 * 256 + (c ^ ((k6 & 15) << 2))];
        p += v * v;
    }
    atomicAdd(&probs[b * 64 + k6], p);
}

// ============================ launch ============================
extern "C" void kernel_launch(void* const* d_in, const int* in_sizes, int n_in,
                              void* d_out, int out_size, void* d_ws, size_t ws_size,
                              hipStream_t stream)
{
    const float* batch  = (const float*)d_in[0];
    const float* w_in1  = (const float*)d_in[1];
    const float* w_in2  = (const float*)d_in[2];
    const float* w_u    = (const float*)d_in[3];
    const float* w_k1   = (const float*)d_in[4];
    const float* w_k2   = (const float*)d_in[5];
    const float* w_out1 = (const float*)d_in[6];
    const float* w_out2 = (const float*)d_in[7];
    const int*   inputs = (const int*)d_in[8];
    float* probs = (float*)d_out;
    float* psi   = (float*)d_out + 2048;      // 32*64 probs, then 32*2^19 psi
    float* tab   = (float*)d_ws;              // 54 tables x 1 MiB float2 = 54 MiB

    tables_kernel<<<dim3(512, 54), 256, 0, stream>>>(w_in1, w_in2, w_k1, w_k2,
                                                     w_out1, w_out2, tab);
    main_kernel<<<512, 256, 0, stream>>>(batch, w_u, inputs, tab, psi, probs, 0);
    main_kernel<<<512, 256, 0, stream>>>(batch, w_u, inputs, tab, psi, probs, 1);
    out_kernel<<<1024, 256, 0, stream>>>(tab, psi, probs);
}